// Round 8
// baseline (496.667 us; speedup 1.0000x reference)
//
#include <hip/hip_runtime.h>

// LinearSelfAttention B=32 P=4 N=1024 D=256 — barrier-free wave-strip form.
// cv = sum_n softmax(q)_n k_n = (y/S)@Wk + b_k,  y = sum_n e_n x_n  (no K).
// out = (relu(x@Wv+b_v) .* cv) @ Wo + b_o   (cv folded A-side in k_vo).
// Anti-convoy design: NO __syncthreads in the heavy kernels. Each wave owns a
// private 16-row strip; all cross-lane data moves via shfl or tiny same-wave
// LDS. Independent waves de-phase, overlapping HBM/VALU/MFMA across the CU.
//   memset : y/Sg zero.
//   k_sum  : 1024 blk x 256 thr, 2 strips/wave. Per strip: 16 coalesced fp32
//            row loads -> per-lane q partial (fp32, 4 wq regs) + bf16 copies
//            -> bf16 chunks stored DIRECTLY to xb (swizzled addr, no LDS)
//            -> q via 6-step shfl butterfly (lane l ends with row l&15's
//            full 256-dot) -> e=exp(q+bq) -> e_s (tiny wave LDS) -> y from
//            register bf16 copies (yacc[4]/lane, 4 atomics at end).
//            Blocks 0..255 also pack Wv/Wo MFMA fragments (k_prep absorbed).
//   k_cv   : cv_g = (y_g/S_g)@Wk + b_k (128 blocks, proven).
//   k_vo   : 2048 blk x 256 thr, 1 strip/wave: 8x global_load_lds DMA ->
//            wave vmcnt(0) -> GEMM-A (16ct x 8kk) -> relu(+bv)*cv -> bf16
//            in-place -> GEMM-B -> out. No barriers (same-wave LDS order).
// GEMMs: mfma_f32_16x16x32_bf16, B pre-packed in fragment order
//   frag[ct][kk][lane][j] = W[kk*32+(lane>>4)*8+j][ct*16+(lane&15)]
// C/D: col = ct*16+(lane&15), row = (lane>>4)*4+reg (16-row strip).
// Strip swizzle: 16B chunk (row,c8) stored at chunk index c8^row (row<16).
// xb strip s (rows 16s..16s+15) = 8KB byte-image of the strip at s*4096 u16.

typedef float  floatx4 __attribute__((ext_vector_type(4)));
typedef __bf16 bf16x8  __attribute__((ext_vector_type(8)));
typedef unsigned short u16;
typedef u16 u16x8 __attribute__((ext_vector_type(8)));
typedef u16 u16x4 __attribute__((ext_vector_type(4)));

#define NGRP 128

__device__ __forceinline__ float bf2f(u16 u) {
    union { unsigned int i; float f; } c; c.i = ((unsigned int)u) << 16; return c.f;
}
__device__ __forceinline__ u16 f2bf(float f) {
    union { __bf16 h; u16 u; } c; c.h = (__bf16)f; return c.u;
}
__device__ __forceinline__ floatx4 mfma16(bf16x8 a, bf16x8 b, floatx4 c) {
    return __builtin_amdgcn_mfma_f32_16x16x32_bf16(a, b, c, 0, 0, 0);
}

// 16B global->LDS DMA. lds must be wave-uniform; HW adds lane*16; src per-lane.
__device__ __forceinline__ void dma16(const u16* src, u16* lds) {
    __builtin_amdgcn_global_load_lds(
        (const __attribute__((address_space(1))) unsigned int*)src,
        (__attribute__((address_space(3))) unsigned int*)lds, 16, 0, 0);
}

// ---------------------------------------------------------------------------
// k_sum: 1024 blocks x 256 threads. Wave w: strips m0 = b*128 + w*16 + s*64,
// s=0,1 (strip id = b*8 + w + s*4 = m0/16). g = b>>3. Barrier-free.
// ---------------------------------------------------------------------------
__global__ __launch_bounds__(256, 4) void k_sum(
    const float* __restrict__ x, const float* __restrict__ Wqkv,
    const float* __restrict__ Wo, const float* __restrict__ bqkv,
    float* __restrict__ y, float* __restrict__ Sg,
    u16* __restrict__ xb, u16* __restrict__ Wvp, u16* __restrict__ Wop)
{
    const int tid = threadIdx.x;
    const int w = tid >> 6, lane = tid & 63;
    const int b = blockIdx.x;
    const int g = b >> 3;

    __shared__ float e_s[4][16];

    // ---- weight packing (absorbs k_prep; consumed only by k_vo) ----
    if (b < 256) {
        const int i = b * 256 + tid;
        const int j = i & 7, pl = (i >> 3) & 63, kk = (i >> 9) & 7, ct = i >> 12;
        const int k = kk * 32 + (pl >> 4) * 8 + j;
        Wvp[i] = f2bf(Wqkv[k * 513 + (257 + ct * 16 + (pl & 15))]);
        Wop[i] = f2bf(Wo[k * 256 + (ct * 16 + (pl & 15))]);
    }

    const float bq0 = bqkv[0];

    // wq slice for this lane's 4 columns (strided dwords, L2-shared)
    float wqv[4];
#pragma unroll
    for (int c = 0; c < 4; ++c) wqv[c] = Wqkv[(size_t)(lane * 4 + c) * 513];

    float yacc[4] = {0.f, 0.f, 0.f, 0.f};
    float Sacc = 0.f;

#pragma unroll
    for (int s = 0; s < 2; ++s) {
        const int m0 = b * 128 + w * 16 + s * 64;
        u16* xt = xb + (size_t)(b * 8 + w + s * 4) * 4096;

        // ---- stage: coalesced fp32 rows -> q partials + bf16 regs -> xb ----
        float p[16];
        u16x4 o[16];
#pragma unroll
        for (int r = 0; r < 16; ++r) {
            floatx4 u = *(const floatx4*)(x + (size_t)(m0 + r) * 256 + lane * 4);
            p[r] = u[0] * wqv[0] + u[1] * wqv[1] + u[2] * wqv[2] + u[3] * wqv[3];
            u16x4 h;
            h[0] = f2bf(u[0]); h[1] = f2bf(u[1]); h[2] = f2bf(u[2]); h[3] = f2bf(u[3]);
            o[r] = h;
            *(u16x4*)(xt + r * 256 + (((lane >> 1) ^ r) * 8 + (lane & 1) * 4)) = h;
        }

        // ---- butterfly: 16 rows x 64 lanes -> lane l holds row (l&15) ----
        float t8[8];
#pragma unroll
        for (int i = 0; i < 8; ++i) {
            const float a = p[2 * i], c = p[2 * i + 1];
            t8[i] = ((lane & 1) ? c : a) + __shfl_xor((lane & 1) ? a : c, 1, 64);
        }
        float t4[4];
#pragma unroll
        for (int i = 0; i < 4; ++i) {
            const float a = t8[2 * i], c = t8[2 * i + 1];
            t4[i] = ((lane & 2) ? c : a) + __shfl_xor((lane & 2) ? a : c, 2, 64);
        }
        float t2[2];
#pragma unroll
        for (int i = 0; i < 2; ++i) {
            const float a = t4[2 * i], c = t4[2 * i + 1];
            t2[i] = ((lane & 4) ? c : a) + __shfl_xor((lane & 4) ? a : c, 4, 64);
        }
        float q;
        {
            const float a = t2[0], c = t2[1];
            q = ((lane & 8) ? c : a) + __shfl_xor((lane & 8) ? a : c, 8, 64);
        }
        q += __shfl_xor(q, 16, 64);
        q += __shfl_xor(q, 32, 64);

        const float e = __expf(q + bq0);
        if (lane < 16) { e_s[w][lane] = e; Sacc += e; }

        // ---- y: lane's 4 cols summed over 16 rows (register-sourced) ----
#pragma unroll
        for (int r = 0; r < 16; ++r) {
            const float er = e_s[w][r];
            yacc[0] += er * bf2f(o[r][0]);
            yacc[1] += er * bf2f(o[r][1]);
            yacc[2] += er * bf2f(o[r][2]);
            yacc[3] += er * bf2f(o[r][3]);
        }
    }

    // ---- final reductions: one S atomic/wave, 4 y atomics/lane ----
#pragma unroll
    for (int m = 1; m <= 32; m <<= 1) Sacc += __shfl_xor(Sacc, m, 64);
    if (lane == 0) atomicAdd(Sg + g, Sacc);
#pragma unroll
    for (int j = 0; j < 4; ++j) atomicAdd(y + g * 256 + lane * 4 + j, yacc[j]);
}

// ---------------------------------------------------------------------------
// k_cv: cv_g = (y_g/S_g) @ Wk + b_k. 128 blocks x 256 threads (proven).
// ---------------------------------------------------------------------------
__global__ __launch_bounds__(256) void k_cv(
    const float* __restrict__ Wqkv, const float* __restrict__ bqkv,
    const float* __restrict__ y, const float* __restrict__ Sg,
    float* __restrict__ cv)
{
    const int g = blockIdx.x, d = threadIdx.x;
    __shared__ float ys[256];
    ys[d] = y[g * 256 + d] * (1.0f / Sg[g]);
    __syncthreads();
    float acc = bqkv[1 + d];
    const float* wp = Wqkv + 1 + d;
#pragma unroll 4
    for (int t = 0; t < 256; t++) acc += ys[t] * wp[(size_t)t * 513];
    cv[g * 256 + d] = acc;
}

// ---------------------------------------------------------------------------
// k_vo: 2048 blocks x 256 threads, 1 strip/wave (j = blockIdx*4 + w).
// DMA xb strip -> wave vmcnt(0) -> GEMM-A -> relu(+bv)*cv -> GEMM-B -> out.
// Barrier-free.
// ---------------------------------------------------------------------------
__global__ __launch_bounds__(256, 4) void k_vo(
    const u16* __restrict__ xb, const u16* __restrict__ Wvp,
    const u16* __restrict__ Wop, const float* __restrict__ cv,
    const float* __restrict__ bqkv, const float* __restrict__ bo,
    float* __restrict__ out)
{
    const int tid = threadIdx.x;
    const int w = tid >> 6, lane = tid & 63;
    const int quad = lane >> 4, n16 = lane & 15;
    const int j = blockIdx.x * 4 + w;     // strip id
    const int m0 = j * 16;
    const int g  = j >> 6;

    __shared__ u16 As[4][4096];
    u16* S = As[w];

    // ---- DMA strip (wave-level; lds base wave-uniform, src per-lane) ----
    {
        const u16* src = xb + (size_t)j * 4096;
#pragma unroll
        for (int i = 0; i < 8; ++i)
            dma16(src + i * 512 + lane * 8, S + i * 512);
    }
    __builtin_amdgcn_sched_barrier(0);
    asm volatile("s_waitcnt vmcnt(0)" ::: "memory");
    __builtin_amdgcn_sched_barrier(0);

    // ---- GEMM-A: v = x @ Wv ----
    floatx4 acc[16];
#pragma unroll
    for (int ct = 0; ct < 16; ++ct) acc[ct] = (floatx4){0.f, 0.f, 0.f, 0.f};
#pragma unroll
    for (int kk = 0; kk < 8; ++kk) {
        bf16x8 a = __builtin_bit_cast(bf16x8,
            *(const u16x8*)(S + n16 * 256 + (((kk * 4 + quad) ^ n16) * 8)));
#pragma unroll
        for (int ct = 0; ct < 16; ++ct) {
            bf16x8 bfr = __builtin_bit_cast(bf16x8,
                *(const u16x8*)(Wvp + (size_t)((ct * 8 + kk) * 64 + lane) * 8));
            acc[ct] = mfma16(a, bfr, acc[ct]);
        }
    }

    // ---- epilogue: v = relu(acc + b_v) * cv -> bf16, in place ----
#pragma unroll
    for (int ct = 0; ct < 16; ++ct) {
        const int col = ct * 16 + n16;
        const float bv = bqkv[257 + col];
        const float cvv = cv[g * 256 + col];
#pragma unroll
        for (int r = 0; r < 4; ++r) {
            const int row = quad * 4 + r;
            S[row * 256 + ((((col >> 3) ^ row) * 8) + (col & 7))] =
                f2bf(fmaxf(acc[ct][r] + bv, 0.f) * cvv);
        }
    }

    // ---- GEMM-B: out = v @ Wo ----
    floatx4 acc2[16];
#pragma unroll
    for (int ct = 0; ct < 16; ++ct) acc2[ct] = (floatx4){0.f, 0.f, 0.f, 0.f};
#pragma unroll
    for (int kk = 0; kk < 8; ++kk) {
        bf16x8 a = __builtin_bit_cast(bf16x8,
            *(const u16x8*)(S + n16 * 256 + (((kk * 4 + quad) ^ n16) * 8)));
#pragma unroll
        for (int ct = 0; ct < 16; ++ct) {
            bf16x8 bfr = __builtin_bit_cast(bf16x8,
                *(const u16x8*)(Wop + (size_t)((ct * 8 + kk) * 64 + lane) * 8));
            acc2[ct] = mfma16(a, bfr, acc2[ct]);
        }
    }

    // ---- out stores ----
#pragma unroll
    for (int ct = 0; ct < 16; ++ct) {
        const int col = ct * 16 + n16;
        const float bb = bo[col];
#pragma unroll
        for (int r = 0; r < 4; ++r)
            out[(size_t)(m0 + quad * 4 + r) * 256 + col] = acc2[ct][r] + bb;
    }
}

// ---------------------------------------------------------------------------
extern "C" void kernel_launch(void* const* d_in, const int* in_sizes, int n_in,
                              void* d_out, int out_size, void* d_ws, size_t ws_size,
                              hipStream_t stream)
{
    const float* x    = (const float*)d_in[0];
    const float* Wqkv = (const float*)d_in[1];
    const float* bqkv = (const float*)d_in[2];
    const float* Wo   = (const float*)d_in[3];
    const float* bo   = (const float*)d_in[4];
    float* out = (float*)d_out;

    char* ws = (char*)d_ws;
    u16*   Wvp = (u16*)(ws);                 //    131,072 B
    u16*   Wop = (u16*)(ws + 131072);        //    131,072 B
    float* cv  = (float*)(ws + 262144);      //    131,072 B
    float* y   = (float*)(ws + 393216);      //    131,072 B
    float* Sg  = (float*)(ws + 524288);      //        512 B
    u16*   xb  = (u16*)(ws + 524800);        // 67,108,864 B (8192 strips x 8KB)
                                             // total 67,633,664 B

    hipMemsetAsync(ws + 393216, 0, 131584, stream);   // y + Sg
    k_sum<<<1024, 256, 0, stream>>>(x, Wqkv, Wo, bqkv, y, Sg, xb, Wvp, Wop);
    k_cv <<<NGRP, 256, 0, stream>>>(Wqkv, bqkv, y, Sg, cv);
    k_vo <<<2048, 256, 0, stream>>>(xb, Wvp, Wop, cv, bqkv, bo, out);
}